// Round 12
// baseline (419.127 us; speedup 1.0000x reference)
//
#include <hip/hip_runtime.h>

typedef __attribute__((ext_vector_type(8))) short s16x8;
typedef __attribute__((ext_vector_type(8))) unsigned short u16x8;
typedef __attribute__((ext_vector_type(4))) float f32x4;

#define LN_EPS 1e-5f

__device__ inline float bf2f(unsigned short u) {
    union { unsigned int i; float f; } x; x.i = ((unsigned int)u) << 16; return x.f;
}
__device__ inline unsigned short f2bf(float f) {
    unsigned int u = __builtin_bit_cast(unsigned int, f);
    u += 0x7FFFu + ((u >> 16) & 1u);
    return (unsigned short)(u >> 16);
}
__device__ inline unsigned int cvt_pk_bf16(float lo, float hi) {
    unsigned int r;
    asm("v_cvt_pk_bf16_f32 %0, %1, %2" : "=v"(r) : "v"(lo), "v"(hi));
    return r;
}
typedef __attribute__((address_space(1))) const unsigned int as1_u32;
typedef __attribute__((address_space(3))) unsigned int as3_u32;
__device__ inline void gl2lds16(const void* g, void* l) {
    __builtin_amdgcn_global_load_lds((as1_u32*)g, (as3_u32*)l, 16, 0, 0);
}

// ---------------------------------------------------------------------------
// Streaming f32 -> bf16 conversion (no barriers -> full HBM BW; doubles as
// an L3 prefetch for the GEMM that follows). n8 = elements/8.
// ---------------------------------------------------------------------------
__global__ __launch_bounds__(256) void cvt_bf16_kernel(
    const float* __restrict__ in, unsigned short* __restrict__ out, int n8)
{
    int i = blockIdx.x * 256 + threadIdx.x;
    const int stride = gridDim.x * 256;
    for (; i < n8; i += stride) {
        const float4 a = ((const float4*)in)[2 * i];
        const float4 b = ((const float4*)in)[2 * i + 1];
        union { unsigned int u[4]; u16x8 v; } r;
        r.u[0] = cvt_pk_bf16(a.x, a.y);
        r.u[1] = cvt_pk_bf16(a.z, a.w);
        r.u[2] = cvt_pk_bf16(b.x, b.y);
        r.u[3] = cvt_pk_bf16(b.z, b.w);
        ((u16x8*)out)[i] = r.v;
    }
}

// ---------------------------------------------------------------------------
// BK=32 2-phase all-bf16 GEMM (proven __syncthreads ping-pong sync):
//   C[z] = A[z](bf16) @ Wb[z](bf16)^T (+bias_scale*bias1+bias2)(+ReLU)
// 256 thr = 4 waves (2x2); tile 128(M) x 128(N); per buffer: A 8KB + B 8KB,
// both staged via global_load_lds w=16 with source chunk^(row&3) XOR and
// read ks^(fr&3). 32KB LDS total -> 4 blocks/CU (launch_bounds 256,4).
// Epilogue (bf16 out): LDS transpose -> 16B/lane contiguous stores.
// M multiple of 128; bf16-out N multiple of 128; f32-out N col-guarded.
// ---------------------------------------------------------------------------
template<int K, bool RELU, bool F32OUT>
__global__ __launch_bounds__(256, 4) void gemm_bf_kernel(
    const unsigned short* __restrict__ A,
    const unsigned short* __restrict__ Wb,
    const float* __restrict__ bias1,
    const float* __restrict__ bias2,
    float bias_scale,
    void* __restrict__ Cv,
    int N, int gx, int gy,
    size_t strideA_mode, size_t lda,
    size_t strideW_mode, size_t strideB_mode,
    size_t strideC_mode, size_t ldc)
{
    constexpr int NSTEP = K / 32;   // even for K in {512, 256}

    // bijective XCD-aware remap (m204)
    const int nwg = gridDim.x, wgid = blockIdx.x;
    const int q8 = nwg >> 3, r8 = nwg & 7;
    const int xcd = wgid & 7, sub = wgid >> 3;
    int p = (xcd < r8 ? xcd * (q8 + 1) : r8 * (q8 + 1) + (xcd - r8) * q8) + sub;
    const int bx = p % gx; p /= gx;
    const int by = p % gy;
    const int bz = p / gy;
    const int n0 = bx * 128, r0 = by * 128;

    __shared__ __align__(16) unsigned char lds[2][16384];  // [A 8K | B 8K]

    const int tid = threadIdx.x, lane = tid & 63, wid = tid >> 6;
    const int fr = lane & 15, ks = lane >> 4;
    const int wr = (wid >> 1) * 64, wc = (wid & 1) * 64;

    // ---- staging coords (A: 2 insts/wave, B: 2 insts/wave) ----
    // I = (wid*2+j)*64 + lane ; row = I>>2 (0..127); chunk = (I&3)^(row&3)
    const int Ia0 = (wid * 2 + 0) * 64 + lane;
    const int Ia1 = (wid * 2 + 1) * 64 + lane;
    const int ar0 = Ia0 >> 2, ac0 = (Ia0 & 3) ^ (ar0 & 3);
    const int ar1 = Ia1 >> 2, ac1 = (Ia1 & 3) ^ (ar1 & 3);
    const unsigned char* Aslab = (const unsigned char*)(A + (size_t)bz * strideA_mode);
    const unsigned char* aSrc0 = Aslab + (size_t)(r0 + ar0) * lda * 2 + ac0 * 16;
    const unsigned char* aSrc1 = Aslab + (size_t)(r0 + ar1) * lda * 2 + ac1 * 16;
    const unsigned char* Wslab = (const unsigned char*)(Wb + (size_t)bz * strideW_mode);
    const int br0 = min(n0 + ar0, N - 1), br1 = min(n0 + ar1, N - 1);
    const unsigned char* bSrc0 = Wslab + (size_t)br0 * K * 2 + ac0 * 16;
    const unsigned char* bSrc1 = Wslab + (size_t)br1 * K * 2 + ac1 * 16;

    f32x4 acc[4][4];
#pragma unroll
    for (int i = 0; i < 4; ++i)
#pragma unroll
        for (int j = 0; j < 4; ++j)
#pragma unroll
            for (int r = 0; r < 4; ++r) acc[i][j][r] = 0.f;

    auto stage = [&](int buf, int t) {
        gl2lds16(aSrc0 + (size_t)t * 64, &lds[buf][(wid * 2 + 0) * 1024]);
        gl2lds16(aSrc1 + (size_t)t * 64, &lds[buf][(wid * 2 + 1) * 1024]);
        gl2lds16(bSrc0 + (size_t)t * 64, &lds[buf][8192 + (wid * 2 + 0) * 1024]);
        gl2lds16(bSrc1 + (size_t)t * 64, &lds[buf][8192 + (wid * 2 + 1) * 1024]);
    };

    auto compute = [&](int buf) {
        const unsigned char* Ab = &lds[buf][0];
        const unsigned char* Bb = &lds[buf][8192];
        const int co = (ks ^ (fr & 3)) << 4;
        s16x8 af[4], bfr[4];
#pragma unroll
        for (int mi = 0; mi < 4; ++mi)
            af[mi] = *(const s16x8*)(Ab + (wr + mi * 16 + fr) * 64 + co);
#pragma unroll
        for (int ni = 0; ni < 4; ++ni)
            bfr[ni] = *(const s16x8*)(Bb + (wc + ni * 16 + fr) * 64 + co);
#pragma unroll
        for (int mi = 0; mi < 4; ++mi)
#pragma unroll
            for (int ni = 0; ni < 4; ++ni)
                acc[mi][ni] = __builtin_amdgcn_mfma_f32_16x16x32_bf16(af[mi], bfr[ni], acc[mi][ni], 0, 0, 0);
    };

    // ---- prologue ----
    stage(0, 0);
    __syncthreads();

    // ---- main loop (NSTEP even): ping-pong, __syncthreads ----
    for (int t = 0; t < NSTEP; t += 2) {
        stage(1, t + 1);
        compute(0);
        __syncthreads();
        if (t + 2 < NSTEP) stage(0, t + 2);
        compute(1);
        __syncthreads();
    }

    // ---- epilogue ----
    if (!F32OUT) {
        // transpose through LDS -> contiguous 16B/lane stores (full sectors)
        unsigned short* Cl = (unsigned short*)&lds[0][0];   // 128x128 bf16 = 32KB
#pragma unroll
        for (int ni = 0; ni < 4; ++ni) {
            const int col = n0 + wc + ni * 16 + fr;
            float bsum = 0.f;
            if (bias1) bsum += bias_scale * bias1[(size_t)bz * strideB_mode + col];
            if (bias2) bsum += bias2[(size_t)bz * strideB_mode + col];
#pragma unroll
            for (int mi = 0; mi < 4; ++mi)
#pragma unroll
                for (int r = 0; r < 4; ++r) {
                    float v = acc[mi][ni][r] + bsum;
                    if (RELU) v = fmaxf(v, 0.f);
                    Cl[(wr + mi * 16 + ks * 4 + r) * 128 + wc + ni * 16 + fr] = f2bf(v);
                }
        }
        __syncthreads();
        unsigned short* Cg = (unsigned short*)Cv + (size_t)bz * strideC_mode;
#pragma unroll
        for (int it = 0; it < 8; ++it) {
            const int c = it * 256 + tid;
            const int row = c >> 4, ch = c & 15;
            u16x8 v = *(const u16x8*)(&Cl[row * 128 + ch * 8]);
            *(u16x8*)(Cg + (size_t)(r0 + row) * ldc + n0 + ch * 8) = v;
        }
    } else {
#pragma unroll
        for (int ni = 0; ni < 4; ++ni) {
            const int col = n0 + wc + ni * 16 + fr;
            if (col < N) {
                float bsum = 0.f;
                if (bias1) bsum += bias_scale * bias1[(size_t)bz * strideB_mode + col];
                if (bias2) bsum += bias2[(size_t)bz * strideB_mode + col];
#pragma unroll
                for (int mi = 0; mi < 4; ++mi)
#pragma unroll
                    for (int r = 0; r < 4; ++r) {
                        const int row = r0 + wr + mi * 16 + ks * 4 + r;
                        float v = acc[mi][ni][r] + bsum;
                        if (RELU) v = fmaxf(v, 0.f);
                        ((float*)Cv)[(size_t)bz * strideC_mode + (size_t)row * ldc + col] = v;
                    }
            }
        }
    }
}

// ---------------------------------------------------------------------------
// Embedding: e[b,d] = mean_s emb[x[b,s], d]
// ---------------------------------------------------------------------------
__global__ __launch_bounds__(512) void embed_kernel(
    const int* __restrict__ x, const float* __restrict__ emb,
    unsigned short* __restrict__ e)
{
    const int b = blockIdx.x;
    __shared__ int xs[128];
    const int tid = threadIdx.x;
    if (tid < 128) xs[tid] = x[b * 128 + tid];
    __syncthreads();
    float s = 0.f;
    for (int i = 0; i < 128; ++i) s += emb[(size_t)xs[i] * 512 + tid];
    e[(size_t)b * 512 + tid] = f2bf(s * (1.f / 128.f));
}

// ---------------------------------------------------------------------------
// Row LayerNorm over D=512 (+opt ReLU), gamma/beta f32, m = row % M.
// ---------------------------------------------------------------------------
template<bool RELU>
__global__ __launch_bounds__(256) void ln_kernel(
    const unsigned short* __restrict__ X,
    const float* __restrict__ G,
    const float* __restrict__ Bt,
    unsigned short* __restrict__ Y,
    int M)
{
    const int row = blockIdx.x;
    const int m = row % M;
    const unsigned short* xr = X + (size_t)row * 512;
    unsigned short* yr = Y + (size_t)row * 512;
    const int tid = threadIdx.x;
    const float x0 = bf2f(xr[tid]), x1 = bf2f(xr[tid + 256]);
    float s = x0 + x1, q = x0 * x0 + x1 * x1;
#pragma unroll
    for (int off = 32; off; off >>= 1) {
        s += __shfl_xor(s, off);
        q += __shfl_xor(q, off);
    }
    __shared__ float red[4][2];
    const int wid = tid >> 6, lane = tid & 63;
    if (lane == 0) { red[wid][0] = s; red[wid][1] = q; }
    __syncthreads();
    s = red[0][0] + red[1][0] + red[2][0] + red[3][0];
    q = red[0][1] + red[1][1] + red[2][1] + red[3][1];
    const float mu = s * (1.f / 512.f);
    const float var = q * (1.f / 512.f) - mu * mu;
    const float rstd = rsqrtf(var + LN_EPS);
    const float* g = G + (size_t)m * 512;
    const float* bt = Bt + (size_t)m * 512;
    float y0 = (x0 - mu) * rstd * g[tid] + bt[tid];
    float y1 = (x1 - mu) * rstd * g[tid + 256] + bt[tid + 256];
    if (RELU) { y0 = fmaxf(y0, 0.f); y1 = fmaxf(y1, 0.f); }
    yr[tid] = f2bf(y0);
    yr[tid + 256] = f2bf(y1);
}

// ---------------------------------------------------------------------------
// MFMA attention: one block per (local_b, h); qkv chunk [64,150,1536] bf16.
// ---------------------------------------------------------------------------
#define KP 72
#define VP 168
__global__ __launch_bounds__(256) void attn_mfma_kernel(
    const unsigned short* __restrict__ qkv, unsigned short* __restrict__ o_att,
    int b0)
{
    const int bl = blockIdx.x >> 3, h = blockIdx.x & 7;
    __shared__ __align__(16) unsigned short k_s[160 * KP];
    __shared__ __align__(16) unsigned short v_t[64 * VP];
    __shared__ __align__(16) unsigned short p_s[4][16 * VP];
    const int tid = threadIdx.x, lane = tid & 63, wid = tid >> 6;
    const int fr = lane & 15, ks = lane >> 4;
    const size_t base = (size_t)bl * (150 * 1536) + h * 64;

    for (int idx = tid; idx < 160 * 8; idx += 256) {
        const int r = idx >> 3, c8 = (idx & 7) * 8;
        u16x8 v;
        if (r < 150) v = *(const u16x8*)(qkv + base + (size_t)r * 1536 + 512 + c8);
        else {
#pragma unroll
            for (int j = 0; j < 8; ++j) v[j] = 0;
        }
        *(u16x8*)(&k_s[r * KP + c8]) = v;
    }
    for (int idx = tid; idx < 160 * 8; idx += 256) {
        const int c8 = idx / 160, r = idx - c8 * 160;
        u16x8 v;
        if (r < 150) v = *(const u16x8*)(qkv + base + (size_t)r * 1536 + 1024 + c8 * 8);
        else {
#pragma unroll
            for (int j = 0; j < 8; ++j) v[j] = 0;
        }
#pragma unroll
        for (int j = 0; j < 8; ++j) v_t[(c8 * 8 + j) * VP + r] = v[j];
    }
    __syncthreads();

    unsigned short* pw = &p_s[wid][0];

    for (int qt = wid; qt < 10; qt += 4) {
        const int qr = (qt * 16 + fr < 150) ? qt * 16 + fr : 149;
        const unsigned short* qp = qkv + base + (size_t)qr * 1536;
        s16x8 qa0 = *(const s16x8*)(qp + ks * 8);
        s16x8 qa1 = *(const s16x8*)(qp + 32 + ks * 8);

        f32x4 acc[10];
#pragma unroll
        for (int t = 0; t < 10; ++t)
#pragma unroll
            for (int r = 0; r < 4; ++r) acc[t][r] = 0.f;
#pragma unroll
        for (int t = 0; t < 10; ++t) {
            s16x8 kb0 = *(const s16x8*)(&k_s[(t * 16 + fr) * KP + ks * 8]);
            s16x8 kb1 = *(const s16x8*)(&k_s[(t * 16 + fr) * KP + 32 + ks * 8]);
            acc[t] = __builtin_amdgcn_mfma_f32_16x16x32_bf16(qa0, kb0, acc[t], 0, 0, 0);
            acc[t] = __builtin_amdgcn_mfma_f32_16x16x32_bf16(qa1, kb1, acc[t], 0, 0, 0);
        }

        const bool v9 = (fr < 6);
        float inv[4];
#pragma unroll
        for (int i = 0; i < 4; ++i) {
            float m = -1e30f;
#pragma unroll
            for (int t = 0; t < 9; ++t) m = fmaxf(m, acc[t][i]);
            if (v9) m = fmaxf(m, acc[9][i]);
#pragma unroll
            for (int off = 1; off < 16; off <<= 1) m = fmaxf(m, __shfl_xor(m, off));
            float s = 0.f;
#pragma unroll
            for (int t = 0; t < 10; ++t) {
                float e = 0.f;
                if (t < 9 || v9) e = __expf(0.125f * (acc[t][i] - m));
                s += e;
                pw[(ks * 4 + i) * VP + t * 16 + fr] = f2bf(e);
            }
#pragma unroll
            for (int off = 1; off < 16; off <<= 1) s += __shfl_xor(s, off);
            inv[i] = 1.f / s;
        }

        f32x4 o[4];
#pragma unroll
        for (int dt = 0; dt < 4; ++dt)
#pragma unroll
            for (int r = 0; r < 4; ++r) o[dt][r] = 0.f;
#pragma unroll
        for (int kc = 0; kc < 5; ++kc) {
            s16x8 pa = *(const s16x8*)(&pw[fr * VP + kc * 32 + ks * 8]);
#pragma unroll
            for (int dt = 0; dt < 4; ++dt) {
                s16x8 vb = *(const s16x8*)(&v_t[(dt * 16 + fr) * VP + kc * 32 + ks * 8]);
                o[dt] = __builtin_amdgcn_mfma_f32_16x16x32_bf16(pa, vb, o[dt], 0, 0, 0);
            }
        }

#pragma unroll
        for (int dt = 0; dt < 4; ++dt) {
            const int d = h * 64 + dt * 16 + fr;
#pragma unroll
            for (int i = 0; i < 4; ++i) {
                const int q = qt * 16 + ks * 4 + i;
                if (q < 150)
                    o_att[((size_t)((b0 + bl) * 150 + q)) * 512 + d] = f2bf(o[dt][i] * inv[i]);
            }
        }
    }
}

// ---------------------------------------------------------------------------
// osum[b,d] = sum_m o_att[b,m,d]
// ---------------------------------------------------------------------------
__global__ __launch_bounds__(512) void osum_kernel(
    const unsigned short* __restrict__ o_att, unsigned short* __restrict__ osum)
{
    const int b = blockIdx.x, tid = threadIdx.x;
    float s = 0.f;
    const unsigned short* p = o_att + (size_t)b * 150 * 512 + tid;
    for (int mm = 0; mm < 150; ++mm) s += bf2f(p[(size_t)mm * 512]);
    osum[(size_t)b * 512 + tid] = f2bf(s);
}

// ---------------------------------------------------------------------------
extern "C" void kernel_launch(void* const* d_in, const int* in_sizes, int n_in,
                              void* d_out, int out_size, void* d_ws, size_t ws_size,
                              hipStream_t stream)
{
    (void)in_sizes; (void)n_in; (void)out_size; (void)ws_size;

    const int*   x          = (const int*)d_in[0];
    const float* emb        = (const float*)d_in[1];
    const float* W1         = (const float*)d_in[2];
    const float* b1         = (const float*)d_in[3];
    const float* ln1_g      = (const float*)d_in[4];
    const float* ln1_b      = (const float*)d_in[5];
    const float* W2         = (const float*)d_in[6];
    const float* b2         = (const float*)d_in[7];
    const float* dbias      = (const float*)d_in[8];
    const float* in_proj_w  = (const float*)d_in[9];
    const float* in_proj_b  = (const float*)d_in[10];
    const float* out_proj_w = (const float*)d_in[11];
    const float* out_proj_b = (const float*)d_in[12];
    const float* norm_g     = (const float*)d_in[13];
    const float* norm_b     = (const float*)d_in[14];
    const float* dec_w1     = (const float*)d_in[15];
    const float* dec_b1     = (const float*)d_in[16];
    const float* dec_w2     = (const float*)d_in[17];
    const float* dec_b2     = (const float*)d_in[18];

    char* ws = (char*)d_ws;
    unsigned short* e_bf  = (unsigned short*)(ws + 0x0);        // [256,512] bf16
    unsigned short* osum  = (unsigned short*)(ws + 0x40000);
    unsigned short* att1  = (unsigned short*)(ws + 0x80000);
    unsigned short* agg   = (unsigned short*)(ws + 0xC0000);
    unsigned short* dec1  = (unsigned short*)(ws + 0x100000);
    unsigned short* h1    = (unsigned short*)(ws + 0x200000);   // [B,M,D] 37.5MB (later o_att)
    unsigned short* mo    = (unsigned short*)(ws + 0x2800000);  // [B,M,D] 37.5MB
    unsigned short* qkvb  = (unsigned short*)(ws + 0x4E00000);  // [64,M,3D] 28.125MB chunk
    unsigned short* Wbf   = (unsigned short*)(ws + 0x6B00000);  // 78.6MB (W1 then W2)
    unsigned short* ipwbf = (unsigned short*)(ws + 0xB600000);  // in_proj bf16 1.5MB
    unsigned short* opwbf = (unsigned short*)(ws + 0xB780000);  // out_proj bf16 0.5MB
    unsigned short* dw1bf = (unsigned short*)(ws + 0xB800000);  // dec_w1 bf16 0.25MB
    unsigned short* dw2bf = (unsigned short*)(ws + 0xB840000);  // dec_w2 bf16 5MB
    unsigned short* o_att = h1;                                  // h1 dead after G2
    // peak ws ≈ 0xC122000 ≈ 194MB

    // 1) embedding mean -> e [256,512]
    embed_kernel<<<256, 512, 0, stream>>>(x, emb, e_bf);

    // 1b) small-weight conversions (independent)
    cvt_bf16_kernel<<<384, 256, 0, stream>>>(in_proj_w, ipwbf, 1536 * 512 / 8);
    cvt_bf16_kernel<<<128, 256, 0, stream>>>(out_proj_w, opwbf, 512 * 512 / 8);
    cvt_bf16_kernel<<<64, 256, 0, stream>>>(dec_w1, dw1bf, 256 * 512 / 8);
    cvt_bf16_kernel<<<1280, 256, 0, stream>>>(dec_w2, dw2bf, 10000 * 256 / 8);

    // 2a) convert W1 -> Wbf (streams at full BW; leaves Wbf L3-warm)
    cvt_bf16_kernel<<<2048, 256, 0, stream>>>(W1, Wbf, 150 * 512 * 512 / 8);

    // 2b) G1: h1[b,m,:] = e[b,:] @ W1bf[m]^T + b1[m]   (gx=4, gy=2, gz=150)
    gemm_bf_kernel<512, false, false><<<4 * 2 * 150, 256, 0, stream>>>(
        e_bf, Wbf, b1, nullptr, 1.f, h1,
        512, 4, 2,
        (size_t)0, 512, (size_t)512 * 512, 512, 512, 76800);

    // 3) LN(ln1_g, ln1_b) + ReLU, in-place on h1
    ln_kernel<true><<<38400, 256, 0, stream>>>(h1, ln1_g, ln1_b, h1, 150);

    // 4a) convert W2 into the SAME Wbf buffer (G1 has finished reading it)
    cvt_bf16_kernel<<<2048, 256, 0, stream>>>(W2, Wbf, 150 * 512 * 512 / 8);

    // 4b) G2: mo = h1 @ W2bf^T + b2 + dbias
    gemm_bf_kernel<512, false, false><<<4 * 2 * 150, 256, 0, stream>>>(
        h1, Wbf, b2, dbias, 1.f, mo,
        512, 4, 2,
        (size_t)512, 76800, (size_t)512 * 512, 512, 512, 76800);

    // 5) per 64-batch chunk: qkv = mo_chunk @ in_proj^T + b, then attention
    for (int c = 0; c < 4; ++c) {
        gemm_bf_kernel<512, false, false><<<12 * 75, 256, 0, stream>>>(
            mo + (size_t)c * 64 * 76800, ipwbf, in_proj_b, nullptr, 1.f, qkvb,
            1536, 12, 75,
            (size_t)0, 512, (size_t)0, 0, 0, 1536);
        attn_mfma_kernel<<<512, 256, 0, stream>>>(qkvb, o_att, c * 64);
    }

    // 6) osum[b,:] = sum_m o_att[b,m,:]
    osum_kernel<<<256, 512, 0, stream>>>(o_att, osum);

    // 7) attended_sum = osum @ out_proj^T + 150*out_proj_b
    gemm_bf_kernel<512, false, false><<<4 * 2, 256, 0, stream>>>(
        osum, opwbf, out_proj_b, nullptr, 150.f, att1,
        512, 4, 2,
        (size_t)0, 512, (size_t)0, 0, 0, 512);

    // 8) agg = LN(attended_sum; norm_g, norm_b)
    ln_kernel<false><<<256, 256, 0, stream>>>(att1, norm_g, norm_b, agg, 1);

    // 9) dec1 = ReLU(agg @ dec_w1^T + dec_b1)   [256,256]
    gemm_bf_kernel<512, true, false><<<2 * 2, 256, 0, stream>>>(
        agg, dw1bf, dec_b1, nullptr, 1.f, dec1,
        256, 2, 2,
        (size_t)0, 512, (size_t)0, 0, 0, 256);

    // 10) out = dec1 @ dec_w2^T + dec_b2   [256,10000] f32, K=256
    gemm_bf_kernel<256, false, true><<<79 * 2, 256, 0, stream>>>(
        dec1, dw2bf, dec_b2, nullptr, 1.f, d_out,
        10000, 79, 2,
        (size_t)0, 256, (size_t)0, 0, 0, 10000);
}

// Round 13
// 397.713 us; speedup vs baseline: 1.0538x; 1.0538x over previous
//
#include <hip/hip_runtime.h>

typedef __attribute__((ext_vector_type(8))) short s16x8;
typedef __attribute__((ext_vector_type(8))) unsigned short u16x8;
typedef __attribute__((ext_vector_type(4))) float f32x4;

#define LN_EPS 1e-5f

__device__ inline float bf2f(unsigned short u) {
    union { unsigned int i; float f; } x; x.i = ((unsigned int)u) << 16; return x.f;
}
__device__ inline unsigned short f2bf(float f) {
    unsigned int u = __builtin_bit_cast(unsigned int, f);
    u += 0x7FFFu + ((u >> 16) & 1u);
    return (unsigned short)(u >> 16);
}
__device__ inline unsigned int cvt_pk_bf16(float lo, float hi) {
    unsigned int r;
    asm("v_cvt_pk_bf16_f32 %0, %1, %2" : "=v"(r) : "v"(lo), "v"(hi));
    return r;
}
typedef __attribute__((address_space(1))) const unsigned int as1_u32;
typedef __attribute__((address_space(3))) unsigned int as3_u32;
__device__ inline void gl2lds16(const void* g, void* l) {
    __builtin_amdgcn_global_load_lds((as1_u32*)g, (as3_u32*)l, 16, 0, 0);
}

__device__ inline void cvt_stream(const float* __restrict__ src,
                                  unsigned short* __restrict__ dst,
                                  int n8, int lb, int nb, int tid)
{
    int i = lb * 256 + tid;
    const int stride = nb * 256;
    for (; i < n8; i += stride) {
        const float4 a = ((const float4*)src)[2 * i];
        const float4 b = ((const float4*)src)[2 * i + 1];
        union { unsigned int u[4]; u16x8 v; } r;
        r.u[0] = cvt_pk_bf16(a.x, a.y);
        r.u[1] = cvt_pk_bf16(a.z, a.w);
        r.u[2] = cvt_pk_bf16(b.x, b.y);
        r.u[3] = cvt_pk_bf16(b.z, b.w);
        ((u16x8*)dst)[i] = r.v;
    }
}

// ---------------------------------------------------------------------------
// prep: embed (blocks 0..255) + cvt W1 (2048) + cvt small weights, one launch.
// ---------------------------------------------------------------------------
__global__ __launch_bounds__(256) void prep_kernel(
    const int* __restrict__ x, const float* __restrict__ emb,
    unsigned short* __restrict__ e,
    const float* __restrict__ w1, unsigned short* __restrict__ w1b,
    const float* __restrict__ ipw, unsigned short* __restrict__ ipwb,
    const float* __restrict__ opw, unsigned short* __restrict__ opwb,
    const float* __restrict__ dw1, unsigned short* __restrict__ dw1b,
    const float* __restrict__ dw2, unsigned short* __restrict__ dw2b)
{
    const int tid = threadIdx.x;
    int b = blockIdx.x;
    if (b < 256) {
        // embedding mean: e[b,d] = mean_s emb[x[b,s],d]; thread covers d, d+256
        __shared__ int xs[128];
        if (tid < 128) xs[tid] = x[b * 128 + tid];
        __syncthreads();
        float s0 = 0.f, s1 = 0.f;
        for (int i = 0; i < 128; ++i) {
            const float* r = emb + (size_t)xs[i] * 512;
            s0 += r[tid]; s1 += r[tid + 256];
        }
        e[(size_t)b * 512 + tid] = f2bf(s0 * (1.f / 128.f));
        e[(size_t)b * 512 + tid + 256] = f2bf(s1 * (1.f / 128.f));
        return;
    }
    b -= 256;
    if (b < 2048) { cvt_stream(w1, w1b, 150 * 512 * 512 / 8, b, 2048, tid); return; }
    b -= 2048;
    if (b < 384) { cvt_stream(ipw, ipwb, 1536 * 512 / 8, b, 384, tid); return; }
    b -= 384;
    if (b < 128) { cvt_stream(opw, opwb, 512 * 512 / 8, b, 128, tid); return; }
    b -= 128;
    if (b < 64) { cvt_stream(dw1, dw1b, 256 * 512 / 8, b, 64, tid); return; }
    b -= 64;
    cvt_stream(dw2, dw2b, 10000 * 256 / 8, b, 1280, tid);
}
#define PREP_BLOCKS (256 + 2048 + 384 + 128 + 64 + 1280)

// ---------------------------------------------------------------------------
// BK=32 2-phase all-bf16 GEMM (proven __syncthreads ping-pong), with optional
// fused tail-conversion blocks (blockIdx >= ngemm stream-convert cvt_src).
//   C[z] = A[z](bf16) @ Wb[z](bf16)^T (+bias_scale*bias1+bias2)(+ReLU)
// 256 thr = 4 waves (2x2); tile 128x128; per buffer A 8KB + B 8KB via
// global_load_lds w=16, source chunk^(row&3) XOR, read ks^(fr&3).
// 32KB LDS -> 4 blocks/CU. Epilogue (bf16): LDS transpose -> 16B stores.
// M multiple of 128; bf16-out N multiple of 128; f32-out N col-guarded.
// ---------------------------------------------------------------------------
template<int K, bool RELU, bool F32OUT>
__global__ __launch_bounds__(256, 4) void gemm_bf_kernel(
    const unsigned short* __restrict__ A,
    const unsigned short* __restrict__ Wb,
    const float* __restrict__ bias1,
    const float* __restrict__ bias2,
    float bias_scale,
    void* __restrict__ Cv,
    int N, int gx, int gy, int ngemm,
    size_t strideA_mode, size_t lda,
    size_t strideW_mode, size_t strideB_mode,
    size_t strideC_mode, size_t ldc,
    const float* __restrict__ cvt_src, unsigned short* __restrict__ cvt_dst,
    int cvt_n8)
{
    constexpr int NSTEP = K / 32;
    const int tid = threadIdx.x;
    const int wgid = blockIdx.x;

    if (wgid >= ngemm) {
        // fused conversion tail
        cvt_stream(cvt_src, cvt_dst, cvt_n8, wgid - ngemm, gridDim.x - ngemm, tid);
        return;
    }

    // bijective XCD-aware remap over the GEMM sub-grid (m204)
    const int q8 = ngemm >> 3, r8 = ngemm & 7;
    const int xcd = wgid & 7, sub = wgid >> 3;
    int p = (xcd < r8 ? xcd * (q8 + 1) : r8 * (q8 + 1) + (xcd - r8) * q8) + sub;
    const int bx = p % gx; p /= gx;
    const int by = p % gy;
    const int bz = p / gy;
    const int n0 = bx * 128, r0 = by * 128;

    __shared__ __align__(16) unsigned char lds[2][16384];  // [A 8K | B 8K]

    const int lane = tid & 63, wid = tid >> 6;
    const int fr = lane & 15, ks = lane >> 4;
    const int wr = (wid >> 1) * 64, wc = (wid & 1) * 64;

    const int Ia0 = (wid * 2 + 0) * 64 + lane;
    const int Ia1 = (wid * 2 + 1) * 64 + lane;
    const int ar0 = Ia0 >> 2, ac0 = (Ia0 & 3) ^ (ar0 & 3);
    const int ar1 = Ia1 >> 2, ac1 = (Ia1 & 3) ^ (ar1 & 3);
    const unsigned char* Aslab = (const unsigned char*)(A + (size_t)bz * strideA_mode);
    const unsigned char* aSrc0 = Aslab + (size_t)(r0 + ar0) * lda * 2 + ac0 * 16;
    const unsigned char* aSrc1 = Aslab + (size_t)(r0 + ar1) * lda * 2 + ac1 * 16;
    const unsigned char* Wslab = (const unsigned char*)(Wb + (size_t)bz * strideW_mode);
    const int br0 = min(n0 + ar0, N - 1), br1 = min(n0 + ar1, N - 1);
    const unsigned char* bSrc0 = Wslab + (size_t)br0 * K * 2 + ac0 * 16;
    const unsigned char* bSrc1 = Wslab + (size_t)br1 * K * 2 + ac1 * 16;

    f32x4 acc[4][4];
#pragma unroll
    for (int i = 0; i < 4; ++i)
#pragma unroll
        for (int j = 0; j < 4; ++j)
#pragma unroll
            for (int r = 0; r < 4; ++r) acc[i][j][r] = 0.f;

    auto stage = [&](int buf, int t) {
        gl2lds16(aSrc0 + (size_t)t * 64, &lds[buf][(wid * 2 + 0) * 1024]);
        gl2lds16(aSrc1 + (size_t)t * 64, &lds[buf][(wid * 2 + 1) * 1024]);
        gl2lds16(bSrc0 + (size_t)t * 64, &lds[buf][8192 + (wid * 2 + 0) * 1024]);
        gl2lds16(bSrc1 + (size_t)t * 64, &lds[buf][8192 + (wid * 2 + 1) * 1024]);
    };

    auto compute = [&](int buf) {
        const unsigned char* Ab = &lds[buf][0];
        const unsigned char* Bb = &lds[buf][8192];
        const int co = (ks ^ (fr & 3)) << 4;
        s16x8 af[4], bfr[4];
#pragma unroll
        for (int mi = 0; mi < 4; ++mi)
            af[mi] = *(const s16x8*)(Ab + (wr + mi * 16 + fr) * 64 + co);
#pragma unroll
        for (int ni = 0; ni < 4; ++ni)
            bfr[ni] = *(const s16x8*)(Bb + (wc + ni * 16 + fr) * 64 + co);
#pragma unroll
        for (int mi = 0; mi < 4; ++mi)
#pragma unroll
            for (int ni = 0; ni < 4; ++ni)
                acc[mi][ni] = __builtin_amdgcn_mfma_f32_16x16x32_bf16(af[mi], bfr[ni], acc[mi][ni], 0, 0, 0);
    };

    stage(0, 0);
    __syncthreads();

    for (int t = 0; t < NSTEP; t += 2) {
        stage(1, t + 1);
        compute(0);
        __syncthreads();
        if (t + 2 < NSTEP) stage(0, t + 2);
        compute(1);
        __syncthreads();
    }

    if (!F32OUT) {
        unsigned short* Cl = (unsigned short*)&lds[0][0];   // 128x128 bf16 = 32KB
#pragma unroll
        for (int ni = 0; ni < 4; ++ni) {
            const int col = n0 + wc + ni * 16 + fr;
            float bsum = 0.f;
            if (bias1) bsum += bias_scale * bias1[(size_t)bz * strideB_mode + col];
            if (bias2) bsum += bias2[(size_t)bz * strideB_mode + col];
#pragma unroll
            for (int mi = 0; mi < 4; ++mi)
#pragma unroll
                for (int r = 0; r < 4; ++r) {
                    float v = acc[mi][ni][r] + bsum;
                    if (RELU) v = fmaxf(v, 0.f);
                    Cl[(wr + mi * 16 + ks * 4 + r) * 128 + wc + ni * 16 + fr] = f2bf(v);
                }
        }
        __syncthreads();
        unsigned short* Cg = (unsigned short*)Cv + (size_t)bz * strideC_mode;
#pragma unroll
        for (int it = 0; it < 8; ++it) {
            const int c = it * 256 + tid;
            const int row = c >> 4, ch = c & 15;
            u16x8 v = *(const u16x8*)(&Cl[row * 128 + ch * 8]);
            *(u16x8*)(Cg + (size_t)(r0 + row) * ldc + n0 + ch * 8) = v;
        }
    } else {
#pragma unroll
        for (int ni = 0; ni < 4; ++ni) {
            const int col = n0 + wc + ni * 16 + fr;
            if (col < N) {
                float bsum = 0.f;
                if (bias1) bsum += bias_scale * bias1[(size_t)bz * strideB_mode + col];
                if (bias2) bsum += bias2[(size_t)bz * strideB_mode + col];
#pragma unroll
                for (int mi = 0; mi < 4; ++mi)
#pragma unroll
                    for (int r = 0; r < 4; ++r) {
                        const int row = r0 + wr + mi * 16 + ks * 4 + r;
                        float v = acc[mi][ni][r] + bsum;
                        if (RELU) v = fmaxf(v, 0.f);
                        ((float*)Cv)[(size_t)bz * strideC_mode + (size_t)row * ldc + col] = v;
                    }
            }
        }
    }
}

// ---------------------------------------------------------------------------
// Row LayerNorm over D=512 (+opt ReLU), gamma/beta f32, m = row % M.
// ---------------------------------------------------------------------------
template<bool RELU>
__global__ __launch_bounds__(256) void ln_kernel(
    const unsigned short* __restrict__ X,
    const float* __restrict__ G,
    const float* __restrict__ Bt,
    unsigned short* __restrict__ Y,
    int M)
{
    const int row = blockIdx.x;
    const int m = row % M;
    const unsigned short* xr = X + (size_t)row * 512;
    unsigned short* yr = Y + (size_t)row * 512;
    const int tid = threadIdx.x;
    const float x0 = bf2f(xr[tid]), x1 = bf2f(xr[tid + 256]);
    float s = x0 + x1, q = x0 * x0 + x1 * x1;
#pragma unroll
    for (int off = 32; off; off >>= 1) {
        s += __shfl_xor(s, off);
        q += __shfl_xor(q, off);
    }
    __shared__ float red[4][2];
    const int wid = tid >> 6, lane = tid & 63;
    if (lane == 0) { red[wid][0] = s; red[wid][1] = q; }
    __syncthreads();
    s = red[0][0] + red[1][0] + red[2][0] + red[3][0];
    q = red[0][1] + red[1][1] + red[2][1] + red[3][1];
    const float mu = s * (1.f / 512.f);
    const float var = q * (1.f / 512.f) - mu * mu;
    const float rstd = rsqrtf(var + LN_EPS);
    const float* g = G + (size_t)m * 512;
    const float* bt = Bt + (size_t)m * 512;
    float y0 = (x0 - mu) * rstd * g[tid] + bt[tid];
    float y1 = (x1 - mu) * rstd * g[tid + 256] + bt[tid + 256];
    if (RELU) { y0 = fmaxf(y0, 0.f); y1 = fmaxf(y1, 0.f); }
    yr[tid] = f2bf(y0);
    yr[tid + 256] = f2bf(y1);
}

// ---------------------------------------------------------------------------
// MFMA attention: one block per (b, h), full qkv [256,150,1536] bf16.
// ---------------------------------------------------------------------------
#define KP 72
#define VP 168
__global__ __launch_bounds__(256) void attn_mfma_kernel(
    const unsigned short* __restrict__ qkv, unsigned short* __restrict__ o_att)
{
    const int b = blockIdx.x >> 3, h = blockIdx.x & 7;
    __shared__ __align__(16) unsigned short k_s[160 * KP];
    __shared__ __align__(16) unsigned short v_t[64 * VP];
    __shared__ __align__(16) unsigned short p_s[4][16 * VP];
    const int tid = threadIdx.x, lane = tid & 63, wid = tid >> 6;
    const int fr = lane & 15, ks = lane >> 4;
    const size_t base = (size_t)b * (150 * 1536) + h * 64;

    for (int idx = tid; idx < 160 * 8; idx += 256) {
        const int r = idx >> 3, c8 = (idx & 7) * 8;
        u16x8 v;
        if (r < 150) v = *(const u16x8*)(qkv + base + (size_t)r * 1536 + 512 + c8);
        else {
#pragma unroll
            for (int j = 0; j < 8; ++j) v[j] = 0;
        }
        *(u16x8*)(&k_s[r * KP + c8]) = v;
    }
    for (int idx = tid; idx < 160 * 8; idx += 256) {
        const int c8 = idx / 160, r = idx - c8 * 160;
        u16x8 v;
        if (r < 150) v = *(const u16x8*)(qkv + base + (size_t)r * 1536 + 1024 + c8 * 8);
        else {
#pragma unroll
            for (int j = 0; j < 8; ++j) v[j] = 0;
        }
#pragma unroll
        for (int j = 0; j < 8; ++j) v_t[(c8 * 8 + j) * VP + r] = v[j];
    }
    __syncthreads();

    unsigned short* pw = &p_s[wid][0];

    for (int qt = wid; qt < 10; qt += 4) {
        const int qr = (qt * 16 + fr < 150) ? qt * 16 + fr : 149;
        const unsigned short* qp = qkv + base + (size_t)qr * 1536;
        s16x8 qa0 = *(const s16x8*)(qp + ks * 8);
        s16x8 qa1 = *(const s16x8*)(qp + 32 + ks * 8);

        f32x4 acc[10];
#pragma unroll
        for (int t = 0; t < 10; ++t)
#pragma unroll
            for (int r = 0; r < 4; ++r) acc[t][r] = 0.f;
#pragma unroll
        for (int t = 0; t < 10; ++t) {
            s16x8 kb0 = *(const s16x8*)(&k_s[(t * 16 + fr) * KP + ks * 8]);
            s16x8 kb1 = *(const s16x8*)(&k_s[(t * 16 + fr) * KP + 32 + ks * 8]);
            acc[t] = __builtin_amdgcn_mfma_f32_16x16x32_bf16(qa0, kb0, acc[t], 0, 0, 0);
            acc[t] = __builtin_amdgcn_mfma_f32_16x16x32_bf16(qa1, kb1, acc[t], 0, 0, 0);
        }

        const bool v9 = (fr < 6);
        float inv[4];
#pragma unroll
        for (int i = 0; i < 4; ++i) {
            float m = -1e30f;
#pragma unroll
            for (int t = 0; t < 9; ++t) m = fmaxf(m, acc[t][i]);
            if (v9) m = fmaxf(m, acc[9][i]);
#pragma unroll
            for (int off = 1; off < 16; off <<= 1) m = fmaxf(m, __shfl_xor(m, off));
            float s = 0.f;
#pragma unroll
            for (int t = 0; t < 10; ++t) {
                float e = 0.f;
                if (t < 9 || v9) e = __expf(0.125f * (acc[t][i] - m));
                s += e;
                pw[(ks * 4 + i) * VP + t * 16 + fr] = f2bf(e);
            }
#pragma unroll
            for (int off = 1; off < 16; off <<= 1) s += __shfl_xor(s, off);
            inv[i] = 1.f / s;
        }

        f32x4 o[4];
#pragma unroll
        for (int dt = 0; dt < 4; ++dt)
#pragma unroll
            for (int r = 0; r < 4; ++r) o[dt][r] = 0.f;
#pragma unroll
        for (int kc = 0; kc < 5; ++kc) {
            s16x8 pa = *(const s16x8*)(&pw[fr * VP + kc * 32 + ks * 8]);
#pragma unroll
            for (int dt = 0; dt < 4; ++dt) {
                s16x8 vb = *(const s16x8*)(&v_t[(dt * 16 + fr) * VP + kc * 32 + ks * 8]);
                o[dt] = __builtin_amdgcn_mfma_f32_16x16x32_bf16(pa, vb, o[dt], 0, 0, 0);
            }
        }

#pragma unroll
        for (int dt = 0; dt < 4; ++dt) {
            const int d = h * 64 + dt * 16 + fr;
#pragma unroll
            for (int i = 0; i < 4; ++i) {
                const int q = qt * 16 + ks * 4 + i;
                if (q < 150)
                    o_att[((size_t)(b * 150 + q)) * 512 + d] = f2bf(o[dt][i] * inv[i]);
            }
        }
    }
}

// ---------------------------------------------------------------------------
// osum[b,d] = sum_m o_att[b,m,d]
// ---------------------------------------------------------------------------
__global__ __launch_bounds__(512) void osum_kernel(
    const unsigned short* __restrict__ o_att, unsigned short* __restrict__ osum)
{
    const int b = blockIdx.x, tid = threadIdx.x;
    float s = 0.f;
    const unsigned short* p = o_att + (size_t)b * 150 * 512 + tid;
    for (int mm = 0; mm < 150; ++mm) s += bf2f(p[(size_t)mm * 512]);
    osum[(size_t)b * 512 + tid] = f2bf(s);
}

// ---------------------------------------------------------------------------
extern "C" void kernel_launch(void* const* d_in, const int* in_sizes, int n_in,
                              void* d_out, int out_size, void* d_ws, size_t ws_size,
                              hipStream_t stream)
{
    (void)in_sizes; (void)n_in; (void)out_size; (void)ws_size;

    const int*   x          = (const int*)d_in[0];
    const float* emb        = (const float*)d_in[1];
    const float* W1         = (const float*)d_in[2];
    const float* b1         = (const float*)d_in[3];
    const float* ln1_g      = (const float*)d_in[4];
    const float* ln1_b      = (const float*)d_in[5];
    const float* W2         = (const float*)d_in[6];
    const float* b2         = (const float*)d_in[7];
    const float* dbias      = (const float*)d_in[8];
    const float* in_proj_w  = (const float*)d_in[9];
    const float* in_proj_b  = (const float*)d_in[10];
    const float* out_proj_w = (const float*)d_in[11];
    const float* out_proj_b = (const float*)d_in[12];
    const float* norm_g     = (const float*)d_in[13];
    const float* norm_b     = (const float*)d_in[14];
    const float* dec_w1     = (const float*)d_in[15];
    const float* dec_b1     = (const float*)d_in[16];
    const float* dec_w2     = (const float*)d_in[17];
    const float* dec_b2     = (const float*)d_in[18];

    char* ws = (char*)d_ws;
    unsigned short* e_bf  = (unsigned short*)(ws + 0x0);         // [256,512] bf16
    unsigned short* osum  = (unsigned short*)(ws + 0x40000);
    unsigned short* att1  = (unsigned short*)(ws + 0x80000);
    unsigned short* agg   = (unsigned short*)(ws + 0xC0000);
    unsigned short* dec1  = (unsigned short*)(ws + 0x100000);
    unsigned short* h1    = (unsigned short*)(ws + 0x200000);    // [B,M,D] 37.5MB (later o_att)
    unsigned short* mo    = (unsigned short*)(ws + 0x2800000);   // [B,M,D] 37.5MB
    unsigned short* qkvf  = (unsigned short*)(ws + 0x4E00000);   // [B,M,3D] 112.5MB
    unsigned short* Wbf1  = (unsigned short*)(ws + 0xBE80000);   // 78.6MB
    unsigned short* Wbf2  = (unsigned short*)(ws + 0x10980000);  // 78.6MB
    unsigned short* ipwbf = (unsigned short*)(ws + 0x15480000);  // 1.5MB
    unsigned short* opwbf = (unsigned short*)(ws + 0x15600000);  // 0.5MB
    unsigned short* dw1bf = (unsigned short*)(ws + 0x15700000);  // 0.25MB
    unsigned short* dw2bf = (unsigned short*)(ws + 0x15800000);  // 5MB
    unsigned short* o_att = h1;                                   // h1 dead after G2
    // peak ws ≈ 0x15D00000 ≈ 350MB (ws_size ≈ 629MB per harness fill)

    // 1) prep: embed + cvt W1 + cvt small weights (one streaming launch)
    prep_kernel<<<PREP_BLOCKS, 256, 0, stream>>>(
        x, emb, e_bf, W1, Wbf1, in_proj_w, ipwbf, out_proj_w, opwbf,
        dec_w1, dw1bf, dec_w2, dw2bf);

    // 2) G1 (1200 gemm blocks) + fused cvt-W2 tail (2048 blocks)
    gemm_bf_kernel<512, false, false><<<1200 + 2048, 256, 0, stream>>>(
        e_bf, Wbf1, b1, nullptr, 1.f, h1,
        512, 4, 2, 1200,
        (size_t)0, 512, (size_t)512 * 512, 512, 512, 76800,
        W2, Wbf2, 150 * 512 * 512 / 8);

    // 3) LN(ln1_g, ln1_b) + ReLU, in-place on h1
    ln_kernel<true><<<38400, 256, 0, stream>>>(h1, ln1_g, ln1_b, h1, 150);

    // 4) G2: mo = h1 @ W2bf^T + b2 + dbias
    gemm_bf_kernel<512, false, false><<<1200, 256, 0, stream>>>(
        h1, Wbf2, b2, dbias, 1.f, mo,
        512, 4, 2, 1200,
        (size_t)512, 76800, (size_t)512 * 512, 512, 512, 76800,
        nullptr, nullptr, 0);

    // 5) qkv = mo @ in_proj^T + in_proj_b  (single launch, 3600 blocks)
    gemm_bf_kernel<512, false, false><<<3600, 256, 0, stream>>>(
        mo, ipwbf, in_proj_b, nullptr, 1.f, qkvf,
        1536, 12, 300, 3600,
        (size_t)0, 512, (size_t)0, 0, 0, 1536,
        nullptr, nullptr, 0);

    // 6) attention per (b,h) -> o_att (single launch)
    attn_mfma_kernel<<<2048, 256, 0, stream>>>(qkvf, o_att);

    // 7) osum[b,:] = sum_m o_att[b,m,:]
    osum_kernel<<<256, 512, 0, stream>>>(o_att, osum);

    // 8) attended_sum = osum @ out_proj^T + 150*out_proj_b
    gemm_bf_kernel<512, false, false><<<8, 256, 0, stream>>>(
        osum, opwbf, out_proj_b, nullptr, 150.f, att1,
        512, 4, 2, 8,
        (size_t)0, 512, (size_t)0, 0, 0, 512,
        nullptr, nullptr, 0);

    // 9) agg = LN(attended_sum; norm_g, norm_b)
    ln_kernel<false><<<256, 256, 0, stream>>>(att1, norm_g, norm_b, agg, 1);

    // 10) dec1 = ReLU(agg @ dec_w1^T + dec_b1)   [256,256]
    gemm_bf_kernel<512, true, false><<<4, 256, 0, stream>>>(
        agg, dw1bf, dec_b1, nullptr, 1.f, dec1,
        256, 2, 2, 4,
        (size_t)0, 512, (size_t)0, 0, 0, 256,
        nullptr, nullptr, 0);

    // 11) out = dec1 @ dec_w2^T + dec_b2   [256,10000] f32, K=256
    gemm_bf_kernel<256, false, true><<<158, 256, 0, stream>>>(
        dec1, dw2bf, dec_b2, nullptr, 1.f, d_out,
        10000, 79, 2, 158,
        (size_t)0, 256, (size_t)0, 0, 0, 10000,
        nullptr, nullptr, 0);
}